// Round 2
// baseline (968.303 us; speedup 1.0000x reference)
//
#include <hip/hip_runtime.h>

// LowBitMLP on MI355X (gfx950).
// R4: deepen the R3 8-phase 256^2 GEMM pipeline.
//   R3 result: MfmaUtil 33%, 786 TF. Diagnosis: (a) vm gate distance only
//   2-3 phases with 1 block/CU => all-wave stalls on L2/HBM latency;
//   (b) P1/P3 ds_reads exposed (issued and waited in the same phase).
// Fix:
//   (a) stage 2 phases earlier: P0(t):A(t+1,k1) P1(t):B(t+1,k1)
//       P2(t):A(t+2,k0 -> buf cur!) P3(t):B(t+2,k0). WAR safe: sX[cur][0]
//       drained at P1(t) close barrier. Gates vmcnt(8), distance 4-5 phases,
//       max 12 vm ops in flight. Tail degrades 8->4->0 (uniform branches).
//   (b) issue all 12 ds_reads of a k-half in P0/P2 read sections; drop
//       explicit lgkmcnt (compiler emits counted waits for visible loads);
//       P1/P3 carry no reads so their MFMA starts at the barrier.
// Ledger (steady state, tile t):
//   gate1 @P1(t): need A/B(t,k1) [issued P0/P1(t-1)]; newer = P2/P3(t-1)
//     (t+1,k0) + P0/P1(t) (t+1,k1) = 8 ops -> vmcnt(8).
//   gate2 @P3(t): need A/B(t+1,k0) [issued P2/P3(t-1)]; newer = P0/P1(t)
//     (t+1,k1) + P2/P3(t) (t+2,k0) = 8 ops -> vmcnt(8).
//
// Memory plan (unchanged):
//   d_out: [0,32M) x_h f16; [32M,64M) tw1 f16   (dead before GEMM2 writes)
//   d_ws : [0,32M) tw2 f16; [32M,160M) h f16 (GEMM1 out, LN1+relu in place)

#define THRESH 0.1f
#define LN_EPS 1e-5f

typedef _Float16 f16x8 __attribute__((ext_vector_type(8)));
typedef float f32x4 __attribute__((ext_vector_type(4)));

typedef __attribute__((address_space(3))) void lds_void;
typedef const __attribute__((address_space(1))) void glob_void;

__device__ __forceinline__ void gld16(const void* g, void* l) {
  __builtin_amdgcn_global_load_lds((glob_void*)g, (lds_void*)l, 16, 0, 0);
}

// ---------------- elementwise prep ----------------

__global__ __launch_bounds__(256) void cvt_x_f16(const float* __restrict__ x,
                                                 _Float16* __restrict__ y) {
  const long i = ((long)blockIdx.x * 256 + threadIdx.x) * 8;
  const float4 v0 = *(const float4*)(x + i);
  const float4 v1 = *(const float4*)(x + i + 4);
  const float a[8] = {v0.x, v0.y, v0.z, v0.w, v1.x, v1.y, v1.z, v1.w};
  f16x8 o;
#pragma unroll
  for (int e = 0; e < 8; ++e) o[e] = (_Float16)a[e];
  *(f16x8*)(y + i) = o;
}

__global__ __launch_bounds__(256) void quant_w(const float* __restrict__ w,
                                               _Float16* __restrict__ t) {
  const long i = ((long)blockIdx.x * 256 + threadIdx.x) * 8;
  const float4 v0 = *(const float4*)(w + i);
  const float4 v1 = *(const float4*)(w + i + 4);
  const float a[8] = {v0.x, v0.y, v0.z, v0.w, v1.x, v1.y, v1.z, v1.w};
  f16x8 o;
#pragma unroll
  for (int e = 0; e < 8; ++e) {
    const float q = (fabsf(a[e]) < THRESH) ? 0.f : (a[e] > 0.f ? 1.f : -1.f);
    o[e] = (_Float16)q;
  }
  *(f16x8*)(t + i) = o;
}

// ---------------- 256^2 8-phase GEMM-BT: C = A(MxK) * B(NxK)^T, fused (acc+b)*s --------
// LDS layout: per buffer, per k-half, 16 fragment blocks of 16rows x 32k
// (1KB each, fragment-contiguous => conflict-free ds_read_b128; staging dest
// is linear chunk index => satisfies global_load_lds wave-uniform+lane*16).

#define BARF()                       \
  __builtin_amdgcn_s_barrier();      \
  asm volatile("" ::: "memory")
#define VMC8() asm volatile("s_waitcnt vmcnt(8)" ::: "memory")
#define VMC4() asm volatile("s_waitcnt vmcnt(4)" ::: "memory")
#define VMC0() asm volatile("s_waitcnt vmcnt(0)" ::: "memory")

#define MFMA_QUAD(m0, AF)                                                                    \
  __builtin_amdgcn_s_setprio(1);                                                             \
  _Pragma("unroll") for (int i = 0; i < 4; ++i)                                              \
  _Pragma("unroll") for (int j = 0; j < 4; ++j)                                              \
      acc[(m0) + i][j] = __builtin_amdgcn_mfma_f32_16x16x32_f16(AF[i], bf[j],                \
                                                                acc[(m0) + i][j], 0, 0, 0); \
  __builtin_amdgcn_s_setprio(0)

template <bool OUT_F16>
__global__ __launch_bounds__(512, 2) void gemm256(const _Float16* __restrict__ A,
                                                  const _Float16* __restrict__ B,
                                                  void* __restrict__ C,
                                                  const float* __restrict__ bias,
                                                  const float* __restrict__ scale,
                                                  int N, int K) {
  __shared__ _Float16 sA[2][2][8192];  // [buf][khalf][16 frag * 512] = 64KB
  __shared__ _Float16 sB[2][2][8192];  // 64KB

  const int tid = threadIdx.x;
  const int lane = tid & 63;
  const int wave = tid >> 6;
  const int wm = wave >> 2;  // 0..1 -> C rows wm*128..+128
  const int wn = wave & 3;   // 0..3 -> C cols wn*64..+64
  const long row0 = (long)blockIdx.y * 256;
  const long col0 = (long)blockIdx.x * 256;

  // Staging: chunk c in [0,1024): frag mb=c>>6, row=mb*16+(c&15), koct=(c>>4)&3.
  const int c0 = tid, c1 = tid + 512;
  const _Float16* pA0 = A + (row0 + ((c0 >> 6) << 4) + (c0 & 15)) * (long)K + (((c0 >> 4) & 3) << 3);
  const _Float16* pA1 = A + (row0 + ((c1 >> 6) << 4) + (c1 & 15)) * (long)K + (((c1 >> 4) & 3) << 3);
  const _Float16* pB0 = B + (col0 + ((c0 >> 6) << 4) + (c0 & 15)) * (long)K + (((c0 >> 4) & 3) << 3);
  const _Float16* pB1 = B + (col0 + ((c1 >> 6) << 4) + (c1 & 15)) * (long)K + (((c1 >> 4) & 3) << 3);

#define STG_A(nx, kh, koff)                     \
  gld16(pA0 + (koff), &sA[nx][kh][c0 * 8]);     \
  gld16(pA1 + (koff), &sA[nx][kh][c1 * 8])
#define STG_B(nx, kh, koff)                     \
  gld16(pB0 + (koff), &sB[nx][kh][c0 * 8]);     \
  gld16(pB1 + (koff), &sB[nx][kh][c1 * 8])

  f32x4 acc[8][4] = {};
  const int nT = K >> 6;
  const int aoff = wm * 8 * 512 + lane * 8;  // elems; frag mf adds mf*512
  const int boff = wn * 4 * 512 + lane * 8;

  // Prologue: tile 0 (both halves) + tile 1 kh0.
  STG_A(0, 0, 0);
  STG_B(0, 0, 0);
  STG_A(0, 1, 32);
  STG_B(0, 1, 32);
  if (nT > 1) {
    STG_A(1, 0, 64);
    STG_B(1, 0, 64);
    VMC8();  // (0,k0) landed; newer = (0,k1) + (1,k0) = 8 ops
  } else {
    VMC4();  // (0,k0) landed; newer = (0,k1) = 4 ops
  }
  BARF();

  for (int t = 0; t < nT; ++t) {
    const int cur = t & 1, nx = cur ^ 1;
    const bool more1 = (t + 1 < nT);
    const bool more2 = (t + 2 < nT);
    const int kn1 = (t + 1) << 6;  // elems along K for tile t+1
    const int kn2 = (t + 2) << 6;

    f16x8 af[4], af2[4], bf[4];

    // ---- P0: issue ALL kh0 reads (af0-3, bf, af4-7); stage A(t+1,k1) ----
#pragma unroll
    for (int i = 0; i < 4; ++i) af[i] = *(const f16x8*)&sA[cur][0][aoff + i * 512];
#pragma unroll
    for (int j = 0; j < 4; ++j) bf[j] = *(const f16x8*)&sB[cur][0][boff + j * 512];
#pragma unroll
    for (int i = 0; i < 4; ++i) af2[i] = *(const f16x8*)&sA[cur][0][aoff + (4 + i) * 512];
    if (more1) { STG_A(nx, 1, kn1 + 32); }
    BARF();
    MFMA_QUAD(0, af);  // compiler emits lgkmcnt(4): af2 still in flight
    BARF();

    // ---- P1: stage B(t+1,k1); gate1 (A/B(t,k1) landed); MFMA kh0 m4-7 ----
    if (more1) {
      STG_B(nx, 1, kn1 + 32);
      VMC8();
    } else {
      VMC0();
    }
    BARF();
    MFMA_QUAD(4, af2);
    BARF();

    // ---- P2: issue ALL kh1 reads; stage A(t+2,k0) into buf cur (WAR: kh0
    //          region of cur drained at P1's closing barrier) ----
#pragma unroll
    for (int i = 0; i < 4; ++i) af[i] = *(const f16x8*)&sA[cur][1][aoff + i * 512];
#pragma unroll
    for (int j = 0; j < 4; ++j) bf[j] = *(const f16x8*)&sB[cur][1][boff + j * 512];
#pragma unroll
    for (int i = 0; i < 4; ++i) af2[i] = *(const f16x8*)&sA[cur][1][aoff + (4 + i) * 512];
    if (more2) { STG_A(cur, 0, kn2); }
    BARF();
    MFMA_QUAD(0, af);
    BARF();

    // ---- P3: stage B(t+2,k0); gate2 (A/B(t+1,k0) landed); MFMA kh1 m4-7 ----
    if (more2) { STG_B(cur, 0, kn2); }
    if (more1) {
      if (more2) VMC8();  // newer = (t+1,k1) + (t+2,k0)
      else       VMC4();  // newer = (t+1,k1) only
    }
    BARF();
    MFMA_QUAD(4, af2);
    BARF();
  }

  // Epilogue: C/D layout col = lane&15, row = (lane>>4)*4 + reg.
  const int qd = lane >> 4, l16 = lane & 15;
#pragma unroll
  for (int nf = 0; nf < 4; ++nf) {
    const long c = col0 + wn * 64 + nf * 16 + l16;
    const float bb = bias[c];
    const float ss = scale[c];
#pragma unroll
    for (int mf = 0; mf < 8; ++mf) {
      const long r = row0 + wm * 128 + mf * 16 + qd * 4;
#pragma unroll
      for (int reg = 0; reg < 4; ++reg) {
        const float v = (acc[mf][nf][reg] + bb) * ss;
        if constexpr (OUT_F16)
          ((_Float16*)C)[(r + reg) * (long)N + c] = (_Float16)v;
        else
          ((float*)C)[(r + reg) * (long)N + c] = v;
      }
    }
  }
}

// ---------------- row LayerNorm kernels ----------------

// D = 8192, f16 in/out, LN*g+b then relu, in place. One block (256 thr) per row.
__global__ __launch_bounds__(256) void ln_relu_rows_f16(_Float16* __restrict__ h,
                                                        const float* __restrict__ g,
                                                        const float* __restrict__ b) {
  const int D = 8192;
  const long base = (long)blockIdx.x * D;
  const int tid = threadIdx.x;
  f16x8 v[4];
  float sum = 0.f, sq = 0.f;
#pragma unroll
  for (int c = 0; c < 4; ++c) {
    v[c] = *(const f16x8*)&h[base + c * 2048 + tid * 8];
#pragma unroll
    for (int e = 0; e < 8; ++e) {
      const float f = (float)v[c][e];
      sum += f;
      sq += f * f;
    }
  }
#pragma unroll
  for (int off = 32; off > 0; off >>= 1) {
    sum += __shfl_down(sum, off);
    sq += __shfl_down(sq, off);
  }
  __shared__ float rs[4], rq[4];
  const int wv = tid >> 6, ln = tid & 63;
  if (ln == 0) { rs[wv] = sum; rq[wv] = sq; }
  __syncthreads();
  sum = rs[0] + rs[1] + rs[2] + rs[3];
  sq = rq[0] + rq[1] + rq[2] + rq[3];
  const float mu = sum / D;
  const float rstd = rsqrtf(sq / D - mu * mu + LN_EPS);
#pragma unroll
  for (int c = 0; c < 4; ++c) {
    const int col = c * 2048 + tid * 8;
    f16x8 o;
#pragma unroll
    for (int e = 0; e < 8; ++e) {
      const float f = ((float)v[c][e] - mu) * rstd * g[col + e] + b[col + e];
      o[e] = (_Float16)fmaxf(f, 0.f);
    }
    *(f16x8*)&h[base + col] = o;
  }
}

// D = 2048, f32, LN*g+b IN PLACE on d_out. One block (256 thr) per row.
__global__ __launch_bounds__(256) void ln_rows_f32_inplace(float* __restrict__ io,
                                                           const float* __restrict__ g,
                                                           const float* __restrict__ b) {
  const int D = 2048;
  const long base = (long)blockIdx.x * D;
  const int tid = threadIdx.x;
  const float4 v0 = *(const float4*)&io[base + tid * 8];
  const float4 v1 = *(const float4*)&io[base + tid * 8 + 4];
  const float a[8] = {v0.x, v0.y, v0.z, v0.w, v1.x, v1.y, v1.z, v1.w};
  float sum = 0.f, sq = 0.f;
#pragma unroll
  for (int e = 0; e < 8; ++e) {
    sum += a[e];
    sq += a[e] * a[e];
  }
#pragma unroll
  for (int off = 32; off > 0; off >>= 1) {
    sum += __shfl_down(sum, off);
    sq += __shfl_down(sq, off);
  }
  __shared__ float rs[4], rq[4];
  const int wv = tid >> 6, ln = tid & 63;
  if (ln == 0) { rs[wv] = sum; rq[wv] = sq; }
  __syncthreads();
  sum = rs[0] + rs[1] + rs[2] + rs[3];
  sq = rq[0] + rq[1] + rq[2] + rq[3];
  const float mu = sum / D;
  const float rstd = rsqrtf(sq / D - mu * mu + LN_EPS);
  const int col = tid * 8;
  float o[8];
#pragma unroll
  for (int e = 0; e < 8; ++e) o[e] = (a[e] - mu) * rstd * g[col + e] + b[col + e];
  *(float4*)&io[base + col] = make_float4(o[0], o[1], o[2], o[3]);
  *(float4*)&io[base + col + 4] = make_float4(o[4], o[5], o[6], o[7]);
}

// ---------------- launch ----------------

extern "C" void kernel_launch(void* const* d_in, const int* in_sizes, int n_in,
                              void* d_out, int out_size, void* d_ws, size_t ws_size,
                              hipStream_t stream) {
  const float* x    = (const float*)d_in[0];
  const float* w1   = (const float*)d_in[1];
  const float* b1   = (const float*)d_in[2];
  const float* s1   = (const float*)d_in[3];
  const float* w2   = (const float*)d_in[4];
  const float* b2   = (const float*)d_in[5];
  const float* s2   = (const float*)d_in[6];
  const float* ln1g = (const float*)d_in[7];
  const float* ln1b = (const float*)d_in[8];
  const float* outg = (const float*)d_in[9];
  const float* outb = (const float*)d_in[10];

  const int N = 8192, D_IN = 2048, D_H = 8192, D_OUT = 2048;
  const size_t MB = 1024 * 1024;
  // Scratch phase-1 buffers live in d_out (64MB); dead before GEMM2 writes it.
  char* ob = (char*)d_out;
  _Float16* xh  = (_Float16*)(ob);            // 32MB
  _Float16* tw1 = (_Float16*)(ob + 32 * MB);  // 32MB
  // Persistent-through-GEMM2 buffers in d_ws (160MB used).
  char* ws = (char*)d_ws;
  _Float16* tw2 = (_Float16*)(ws);            // 32MB
  _Float16* h   = (_Float16*)(ws + 32 * MB);  // 128MB

  // elementwise prep: each block handles 2048 elems
  cvt_x_f16<<<(N * D_IN) / 2048, 256, 0, stream>>>(x, xh);
  quant_w<<<(D_H * D_IN) / 2048, 256, 0, stream>>>(w1, tw1);
  quant_w<<<(D_OUT * D_H) / 2048, 256, 0, stream>>>(w2, tw2);

  // layer 1: h = (x @ tw1^T + b1) * s1   -> f16
  gemm256<true><<<dim3(D_H / 256, N / 256), 512, 0, stream>>>(xh, tw1, h, b1, s1, D_H, D_IN);
  // LN + relu in place
  ln_relu_rows_f16<<<N, 256, 0, stream>>>(h, ln1g, ln1b);

  // layer 2: (h @ tw2^T + b2) * s2 -> f32, straight into d_out (xh/tw1 dead)
  gemm256<false><<<dim3(D_OUT / 256, N / 256), 512, 0, stream>>>(h, tw2, d_out, b2, s2, D_OUT, D_H);
  // final LN in place on d_out
  ln_rows_f32_inplace<<<N, 256, 0, stream>>>((float*)d_out, outg, outb);
}

// Round 3
// 917.266 us; speedup vs baseline: 1.0556x; 1.0556x over previous
//
#include <hip/hip_runtime.h>

// LowBitMLP on MI355X (gfx950).
// R5: (a) chunked XCD swizzle (T1) on both GEMMs. R4 PMC: GEMM2 FETCH=1.05GB
//     = A(h,128MB) fetched 8x (once per col-block pass), 3TB/s fetch-bound.
//     The 8 blocks sharing an A panel land on 8 different XCDs (round-robin)
//     -> 8 private-L2 copies. Chunked swizzle gives each XCD 4 row-panels x
//     all cols; per-K-step footprint/XCD ~384KB << 4MB L2 -> A slice fetched
//     once per XCD. Bijective: nwg (256, 1024) divisible by 8.
// (b) revert R4's 2-phase-earlier staging (regressed: DS-pipe contention
//     from stage-into-cur during read phases, 12-deep vm queue; total
//     902->968). Back to the verified R3 ledger (vmcnt(4) gates), KEEPING
//     the af2 read-ahead so P1/P3 have no exposed ds_reads.
// Ledger (steady state, tile t, buf cur):
//   stages: A(t+1,k0)@P0  B(t+1,k0)@P1  A(t+1,k1)@P2  B(t+1,k1)@P3  (2 vm ops each)
//   gate kh1(t) @P1: after STG_B -> outstanding {A(t,k1),B(t,k1),A(t+1,k0),
//     B(t+1,k0)} = 8; vmcnt(4) certifies A/B(t,k1); barrier -> P2 reads safe.
//   gate kh0(t+1) @P3: outstanding {A(t+1,k0),B(t+1,k0),A(t+1,k1),B(t+1,k1)}
//     = 8; vmcnt(4) certifies A/B(t+1,k0); barrier -> P0(t+1) reads safe.
//   WAR: each staged region's last reader finished >= 2 barriers earlier.
//
// Memory plan (unchanged):
//   d_out: [0,32M) x_h f16; [32M,64M) tw1 f16   (dead before GEMM2 writes)
//   d_ws : [0,32M) tw2 f16; [32M,160M) h f16 (GEMM1 out, LN1+relu in place)

#define THRESH 0.1f
#define LN_EPS 1e-5f

typedef _Float16 f16x8 __attribute__((ext_vector_type(8)));
typedef float f32x4 __attribute__((ext_vector_type(4)));

typedef __attribute__((address_space(3))) void lds_void;
typedef const __attribute__((address_space(1))) void glob_void;

__device__ __forceinline__ void gld16(const void* g, void* l) {
  __builtin_amdgcn_global_load_lds((glob_void*)g, (lds_void*)l, 16, 0, 0);
}

// ---------------- elementwise prep ----------------

__global__ __launch_bounds__(256) void cvt_x_f16(const float* __restrict__ x,
                                                 _Float16* __restrict__ y) {
  const long i = ((long)blockIdx.x * 256 + threadIdx.x) * 8;
  const float4 v0 = *(const float4*)(x + i);
  const float4 v1 = *(const float4*)(x + i + 4);
  const float a[8] = {v0.x, v0.y, v0.z, v0.w, v1.x, v1.y, v1.z, v1.w};
  f16x8 o;
#pragma unroll
  for (int e = 0; e < 8; ++e) o[e] = (_Float16)a[e];
  *(f16x8*)(y + i) = o;
}

__global__ __launch_bounds__(256) void quant_w(const float* __restrict__ w,
                                               _Float16* __restrict__ t) {
  const long i = ((long)blockIdx.x * 256 + threadIdx.x) * 8;
  const float4 v0 = *(const float4*)(w + i);
  const float4 v1 = *(const float4*)(w + i + 4);
  const float a[8] = {v0.x, v0.y, v0.z, v0.w, v1.x, v1.y, v1.z, v1.w};
  f16x8 o;
#pragma unroll
  for (int e = 0; e < 8; ++e) {
    const float q = (fabsf(a[e]) < THRESH) ? 0.f : (a[e] > 0.f ? 1.f : -1.f);
    o[e] = (_Float16)q;
  }
  *(f16x8*)(t + i) = o;
}

// ---------------- 256^2 8-phase GEMM-BT: C = A(MxK) * B(NxK)^T, fused (acc+b)*s --------
// LDS layout: per buffer, per k-half, 16 fragment blocks of 16rows x 32k
// (1KB each, fragment-contiguous => conflict-free ds_read_b128; staging dest
// is linear chunk index => satisfies global_load_lds wave-uniform+lane*16).

#define BARF()                       \
  __builtin_amdgcn_s_barrier();      \
  asm volatile("" ::: "memory")
#define VMC4() asm volatile("s_waitcnt vmcnt(4)" ::: "memory")
#define VMC0() asm volatile("s_waitcnt vmcnt(0)" ::: "memory")

#define MFMA_QUAD(m0, AF)                                                                    \
  __builtin_amdgcn_s_setprio(1);                                                             \
  _Pragma("unroll") for (int i = 0; i < 4; ++i)                                              \
  _Pragma("unroll") for (int j = 0; j < 4; ++j)                                              \
      acc[(m0) + i][j] = __builtin_amdgcn_mfma_f32_16x16x32_f16(AF[i], bf[j],                \
                                                                acc[(m0) + i][j], 0, 0, 0); \
  __builtin_amdgcn_s_setprio(0)

template <bool OUT_F16>
__global__ __launch_bounds__(512, 2) void gemm256(const _Float16* __restrict__ A,
                                                  const _Float16* __restrict__ B,
                                                  void* __restrict__ C,
                                                  const float* __restrict__ bias,
                                                  const float* __restrict__ scale,
                                                  int N, int K) {
  __shared__ _Float16 sA[2][2][8192];  // [buf][khalf][16 frag * 512] = 64KB
  __shared__ _Float16 sB[2][2][8192];  // 64KB

  const int tid = threadIdx.x;
  const int lane = tid & 63;
  const int wave = tid >> 6;
  const int wm = wave >> 2;  // 0..1 -> C rows wm*128..+128
  const int wn = wave & 3;   // 0..3 -> C cols wn*64..+64

  // T1 chunked XCD swizzle: hw id round-robins XCDs (xcd = hw%8); give each
  // XCD a contiguous logical chunk so blocks sharing an A row-panel (and the
  // whole B) resolve in one XCD's L2. Bijective since nwg % 8 == 0 here.
  const int gx = gridDim.x;
  const int nwg = gx * gridDim.y;
  const int hw = blockIdx.y * gx + blockIdx.x;
  const int logical = (hw & 7) * (nwg >> 3) + (hw >> 3);
  const int bx = logical % gx;
  const int by = logical / gx;
  const long row0 = (long)by * 256;
  const long col0 = (long)bx * 256;

  // Staging: chunk c in [0,1024): frag mb=c>>6, row=mb*16+(c&15), koct=(c>>4)&3.
  const int c0 = tid, c1 = tid + 512;
  const _Float16* pA0 = A + (row0 + ((c0 >> 6) << 4) + (c0 & 15)) * (long)K + (((c0 >> 4) & 3) << 3);
  const _Float16* pA1 = A + (row0 + ((c1 >> 6) << 4) + (c1 & 15)) * (long)K + (((c1 >> 4) & 3) << 3);
  const _Float16* pB0 = B + (col0 + ((c0 >> 6) << 4) + (c0 & 15)) * (long)K + (((c0 >> 4) & 3) << 3);
  const _Float16* pB1 = B + (col0 + ((c1 >> 6) << 4) + (c1 & 15)) * (long)K + (((c1 >> 4) & 3) << 3);

#define STG_A(nx, kh, koff)                     \
  gld16(pA0 + (koff), &sA[nx][kh][c0 * 8]);     \
  gld16(pA1 + (koff), &sA[nx][kh][c1 * 8])
#define STG_B(nx, kh, koff)                     \
  gld16(pB0 + (koff), &sB[nx][kh][c0 * 8]);     \
  gld16(pB1 + (koff), &sB[nx][kh][c1 * 8])

  f32x4 acc[8][4] = {};
  const int nT = K >> 6;
  const int aoff = wm * 8 * 512 + lane * 8;  // elems; frag mf adds mf*512
  const int boff = wn * 4 * 512 + lane * 8;

  // Prologue: tile 0 -> buf 0; certify kh0 (leaves A/B(0,k1) outstanding).
  STG_A(0, 0, 0);
  STG_B(0, 0, 0);
  STG_A(0, 1, 32);
  STG_B(0, 1, 32);
  VMC4();
  BARF();

  for (int t = 0; t < nT; ++t) {
    const int cur = t & 1, nx = cur ^ 1;
    const bool more1 = (t + 1 < nT);
    const int kn1 = (t + 1) << 6;  // elems along K for tile t+1

    f16x8 af[4], af2[4], bf[4];

    // ---- P0: issue ALL kh0 reads (af0-3, bf, af4-7); stage A(t+1,k0) ----
#pragma unroll
    for (int i = 0; i < 4; ++i) af[i] = *(const f16x8*)&sA[cur][0][aoff + i * 512];
#pragma unroll
    for (int j = 0; j < 4; ++j) bf[j] = *(const f16x8*)&sB[cur][0][boff + j * 512];
#pragma unroll
    for (int i = 0; i < 4; ++i) af2[i] = *(const f16x8*)&sA[cur][0][aoff + (4 + i) * 512];
    if (more1) { STG_A(nx, 0, kn1); }
    BARF();
    MFMA_QUAD(0, af);  // compiler emits counted lgkmcnt: af2 still in flight
    BARF();

    // ---- P1: stage B(t+1,k0); gate kh1(t); MFMA kh0 m4-7 ----
    if (more1) {
      STG_B(nx, 0, kn1);
      VMC4();  // A/B(t,k1) landed; newer = A/B(t+1,k0)
    } else {
      VMC0();  // last tile: only A/B(t,k1) outstanding
    }
    BARF();
    MFMA_QUAD(4, af2);
    BARF();

    // ---- P2: issue ALL kh1 reads; stage A(t+1,k1) ----
#pragma unroll
    for (int i = 0; i < 4; ++i) af[i] = *(const f16x8*)&sA[cur][1][aoff + i * 512];
#pragma unroll
    for (int j = 0; j < 4; ++j) bf[j] = *(const f16x8*)&sB[cur][1][boff + j * 512];
#pragma unroll
    for (int i = 0; i < 4; ++i) af2[i] = *(const f16x8*)&sA[cur][1][aoff + (4 + i) * 512];
    if (more1) { STG_A(nx, 1, kn1 + 32); }
    BARF();
    MFMA_QUAD(0, af);
    BARF();

    // ---- P3: stage B(t+1,k1); gate kh0(t+1); MFMA kh1 m4-7 ----
    if (more1) {
      STG_B(nx, 1, kn1 + 32);
      VMC4();  // A/B(t+1,k0) landed; newer = A/B(t+1,k1)
    }
    BARF();
    MFMA_QUAD(4, af2);
    BARF();
  }

  // Epilogue: C/D layout col = lane&15, row = (lane>>4)*4 + reg.
  const int qd = lane >> 4, l16 = lane & 15;
#pragma unroll
  for (int nf = 0; nf < 4; ++nf) {
    const long c = col0 + wn * 64 + nf * 16 + l16;
    const float bb = bias[c];
    const float ss = scale[c];
#pragma unroll
    for (int mf = 0; mf < 8; ++mf) {
      const long r = row0 + wm * 128 + mf * 16 + qd * 4;
#pragma unroll
      for (int reg = 0; reg < 4; ++reg) {
        const float v = (acc[mf][nf][reg] + bb) * ss;
        if constexpr (OUT_F16)
          ((_Float16*)C)[(r + reg) * (long)N + c] = (_Float16)v;
        else
          ((float*)C)[(r + reg) * (long)N + c] = v;
      }
    }
  }
}

// ---------------- row LayerNorm kernels ----------------

// D = 8192, f16 in/out, LN*g+b then relu, in place. One block (256 thr) per row.
__global__ __launch_bounds__(256) void ln_relu_rows_f16(_Float16* __restrict__ h,
                                                        const float* __restrict__ g,
                                                        const float* __restrict__ b) {
  const int D = 8192;
  const long base = (long)blockIdx.x * D;
  const int tid = threadIdx.x;
  f16x8 v[4];
  float sum = 0.f, sq = 0.f;
#pragma unroll
  for (int c = 0; c < 4; ++c) {
    v[c] = *(const f16x8*)&h[base + c * 2048 + tid * 8];
#pragma unroll
    for (int e = 0; e < 8; ++e) {
      const float f = (float)v[c][e];
      sum += f;
      sq += f * f;
    }
  }
#pragma unroll
  for (int off = 32; off > 0; off >>= 1) {
    sum += __shfl_down(sum, off);
    sq += __shfl_down(sq, off);
  }
  __shared__ float rs[4], rq[4];
  const int wv = tid >> 6, ln = tid & 63;
  if (ln == 0) { rs[wv] = sum; rq[wv] = sq; }
  __syncthreads();
  sum = rs[0] + rs[1] + rs[2] + rs[3];
  sq = rq[0] + rq[1] + rq[2] + rq[3];
  const float mu = sum / D;
  const float rstd = rsqrtf(sq / D - mu * mu + LN_EPS);
#pragma unroll
  for (int c = 0; c < 4; ++c) {
    const int col = c * 2048 + tid * 8;
    f16x8 o;
#pragma unroll
    for (int e = 0; e < 8; ++e) {
      const float f = ((float)v[c][e] - mu) * rstd * g[col + e] + b[col + e];
      o[e] = (_Float16)fmaxf(f, 0.f);
    }
    *(f16x8*)&h[base + col] = o;
  }
}

// D = 2048, f32, LN*g+b IN PLACE on d_out. One block (256 thr) per row.
__global__ __launch_bounds__(256) void ln_rows_f32_inplace(float* __restrict__ io,
                                                           const float* __restrict__ g,
                                                           const float* __restrict__ b) {
  const int D = 2048;
  const long base = (long)blockIdx.x * D;
  const int tid = threadIdx.x;
  const float4 v0 = *(const float4*)&io[base + tid * 8];
  const float4 v1 = *(const float4*)&io[base + tid * 8 + 4];
  const float a[8] = {v0.x, v0.y, v0.z, v0.w, v1.x, v1.y, v1.z, v1.w};
  float sum = 0.f, sq = 0.f;
#pragma unroll
  for (int e = 0; e < 8; ++e) {
    sum += a[e];
    sq += a[e] * a[e];
  }
#pragma unroll
  for (int off = 32; off > 0; off >>= 1) {
    sum += __shfl_down(sum, off);
    sq += __shfl_down(sq, off);
  }
  __shared__ float rs[4], rq[4];
  const int wv = tid >> 6, ln = tid & 63;
  if (ln == 0) { rs[wv] = sum; rq[wv] = sq; }
  __syncthreads();
  sum = rs[0] + rs[1] + rs[2] + rs[3];
  sq = rq[0] + rq[1] + rq[2] + rq[3];
  const float mu = sum / D;
  const float rstd = rsqrtf(sq / D - mu * mu + LN_EPS);
  const int col = tid * 8;
  float o[8];
#pragma unroll
  for (int e = 0; e < 8; ++e) o[e] = (a[e] - mu) * rstd * g[col + e] + b[col + e];
  *(float4*)&io[base + col] = make_float4(o[0], o[1], o[2], o[3]);
  *(float4*)&io[base + col + 4] = make_float4(o[4], o[5], o[6], o[7]);
}

// ---------------- launch ----------------

extern "C" void kernel_launch(void* const* d_in, const int* in_sizes, int n_in,
                              void* d_out, int out_size, void* d_ws, size_t ws_size,
                              hipStream_t stream) {
  const float* x    = (const float*)d_in[0];
  const float* w1   = (const float*)d_in[1];
  const float* b1   = (const float*)d_in[2];
  const float* s1   = (const float*)d_in[3];
  const float* w2   = (const float*)d_in[4];
  const float* b2   = (const float*)d_in[5];
  const float* s2   = (const float*)d_in[6];
  const float* ln1g = (const float*)d_in[7];
  const float* ln1b = (const float*)d_in[8];
  const float* outg = (const float*)d_in[9];
  const float* outb = (const float*)d_in[10];

  const int N = 8192, D_IN = 2048, D_H = 8192, D_OUT = 2048;
  const size_t MB = 1024 * 1024;
  // Scratch phase-1 buffers live in d_out (64MB); dead before GEMM2 writes it.
  char* ob = (char*)d_out;
  _Float16* xh  = (_Float16*)(ob);            // 32MB
  _Float16* tw1 = (_Float16*)(ob + 32 * MB);  // 32MB
  // Persistent-through-GEMM2 buffers in d_ws (160MB used).
  char* ws = (char*)d_ws;
  _Float16* tw2 = (_Float16*)(ws);            // 32MB
  _Float16* h   = (_Float16*)(ws + 32 * MB);  // 128MB

  // elementwise prep: each block handles 2048 elems
  cvt_x_f16<<<(N * D_IN) / 2048, 256, 0, stream>>>(x, xh);
  quant_w<<<(D_H * D_IN) / 2048, 256, 0, stream>>>(w1, tw1);
  quant_w<<<(D_OUT * D_H) / 2048, 256, 0, stream>>>(w2, tw2);

  // layer 1: h = (x @ tw1^T + b1) * s1   -> f16
  gemm256<true><<<dim3(D_H / 256, N / 256), 512, 0, stream>>>(xh, tw1, h, b1, s1, D_H, D_IN);
  // LN + relu in place
  ln_relu_rows_f16<<<N, 256, 0, stream>>>(h, ln1g, ln1b);

  // layer 2: (h @ tw2^T + b2) * s2 -> f32, straight into d_out (xh/tw1 dead)
  gemm256<false><<<dim3(D_OUT / 256, N / 256), 512, 0, stream>>>(h, tw2, d_out, b2, s2, D_OUT, D_H);
  // final LN in place on d_out
  ln_rows_f32_inplace<<<N, 256, 0, stream>>>((float*)d_out, outg, outb);
}